// Round 7
// baseline (281.131 us; speedup 1.0000x reference)
//
#include <hip/hip_runtime.h>
#include <hip/hip_bf16.h>

#define E_DIM 128
#define L_DIM 64
#define HDIM 64

__device__ __forceinline__ float waveSum(float v) {
#pragma unroll
  for (int o = 32; o > 0; o >>= 1) v += __shfl_xor(v, o);
  return v;
}
__device__ __forceinline__ float waveMax(float v) {
#pragma unroll
  for (int o = 32; o > 0; o >>= 1) v = fmaxf(v, __shfl_xor(v, o));
  return v;
}

__device__ __forceinline__ unsigned int f2bf(float f) {  // RNE
  unsigned int u = __float_as_uint(f);
  return (u + 0x7fffu + ((u >> 16) & 1u)) >> 16;
}
__device__ __forceinline__ float lo_bf(unsigned int q) {
  return __uint_as_float(q << 16);
}
__device__ __forceinline__ float hi_bf(unsigned int q) {
  return __uint_as_float(q & 0xffff0000u);
}

// One wave per table row: fp32 -> bf16 convert + per-row projection dots
// with up to three w tails. Lane = dim pair.
__global__ __launch_bounds__(256) void convert_proj(
    const float* __restrict__ src, unsigned short* __restrict__ dst,
    const float* __restrict__ wA, const float* __restrict__ wB,
    const float* __restrict__ wC, float* __restrict__ pA,
    float* __restrict__ pB, float* __restrict__ pC, int rows, int nproj) {
  const int lane = threadIdx.x & 63;
  const int r = blockIdx.x * 4 + (threadIdx.x >> 6);
  if (r >= rows) return;

  const float2 v = *(const float2*)(src + (long)r * E_DIM + lane * 2);
  const unsigned int lo = f2bf(v.x), hi = f2bf(v.y);
  ((unsigned int*)dst)[(long)r * (E_DIM / 2) + lane] = lo | (hi << 16);
  const float x = __uint_as_float(lo << 16);  // rounded values
  const float y = __uint_as_float(hi << 16);

  const float2 a2 = *(const float2*)(wA + E_DIM + lane * 2);
  const float dA = waveSum(x * a2.x + y * a2.y);
  const float2 b2 = *(const float2*)(wB + E_DIM + lane * 2);
  const float dB = waveSum(x * b2.x + y * b2.y);
  float dC = 0.f;
  if (nproj == 3) {
    const float2 c2 = *(const float2*)(wC + E_DIM + lane * 2);
    dC = waveSum(x * c2.x + y * c2.y);
  }
  if (lane == 0) {
    pA[r] = dA;
    pB[r] = dB;
    if (nproj == 3) pC[r] = dC;
  }
}

// One wave per (b, k). Logits via precomputed row projections (no per-
// neighbor butterflies); softmax = 2 butterflies; then one coalesced
// streaming weighted-sum pass over the bf16 rows.
__global__ __launch_bounds__(256) void phase1_proj(
    const float* __restrict__ user_embs,  // fp32 (self rows)
    const unsigned short* __restrict__ user_bf,
    const unsigned short* __restrict__ item_bf,
    const float* __restrict__ projU0, const float* __restrict__ projU1,
    const float* __restrict__ projU2, const float* __restrict__ projI1,
    const float* __restrict__ projI2,
    const float* __restrict__ w_uu, const float* __restrict__ w_uiu,
    const float* __restrict__ w_uui, const float* __restrict__ W0,
    const float* __restrict__ b0, const float* __restrict__ w1,
    const int* __restrict__ uid, const int* __restrict__ nbr,
    const int* __restrict__ uiu, const int* __restrict__ uui,
    float* __restrict__ feats,     // [3][B][E]
    float* __restrict__ partials,  // [3][B]
    int B) {
  const int lane = threadIdx.x & 63;
  const int wv = threadIdx.x >> 6;
  const int w_id = blockIdx.x * 4 + wv;
  const int b = w_id / 3;
  const int k = w_id - 3 * b;
  if (b >= B) return;  // grid exact for B%4==0

  __shared__ float sc[4][E_DIM];

  const int u = uid[b];
  const float2 self = *(const float2*)(user_embs + (long)u * E_DIM + lane * 2);

  const float* w = (k == 0) ? w_uu : (k == 1) ? w_uiu : w_uui;
  const float2 wa = *(const float2*)(w + lane * 2);
  const float2 wb = *(const float2*)(w + E_DIM + lane * 2);
  const float S1 = waveSum(self.x * wa.x + self.y * wa.y);
  const float S2 = waveSum(self.x * wb.x + self.y * wb.y);

  const bool is_uu = (k == 0);
  const float scale = is_uu ? 0.5f : (1.0f / 3.0f);
  // tables: k==0 -> user; k==1 (uiu) -> item,user; k==2 (uui) -> user,item
  const unsigned int* t0 = (const unsigned int*)((k == 1) ? item_bf : user_bf);
  const unsigned int* t1 = (const unsigned int*)((k == 1) ? user_bf : item_bf);
  const float* p0 = (k == 0) ? projU0 : (k == 1) ? projI1 : projU2;
  const float* p1 = (k == 1) ? projU1 : projI2;  // unused for k==0

  // lane l owns neighbor l's indices (coalesced)
  int i0_l, i1_l;
  if (is_uu) {
    i0_l = nbr[b * L_DIM + lane];
    i1_l = 0;
  } else {
    const int* mp = (k == 1) ? uiu : uui;
    i0_l = mp[(b * 2 + 0) * L_DIM + lane];
    i1_l = mp[(b * 2 + 1) * L_DIM + lane];
  }

  // ---- logits from projections (lane = neighbor, no shuffles) ----
  float d = p0[i0_l];
  if (!is_uu) d += p1[i1_l];
  float logit = S1 + scale * (S2 + d);
  logit = (logit > 0.f) ? logit : 0.01f * logit;  // leaky_relu
  if (i0_l == 0) logit += -100000000.0f;          // mask

  const float M = waveMax(logit);
  const float p = __expf(logit - M);
  const float Z = waveSum(p);
  const float a_l = p / Z;  // lane l holds neighbor l's attention weight

  // ---- weighted sum: lane = dim pair, rows streamed once, coalesced ----
  float o0 = 0.f, o1 = 0.f;
#pragma unroll 8
  for (int l = 0; l < L_DIM; ++l) {
    const float a = __shfl(a_l, l);
    const int i0 = __shfl(i0_l, l);
    const unsigned int q0 = t0[i0 * (E_DIM / 2) + lane];
    float h0 = lo_bf(q0), h1 = hi_bf(q0);
    if (!is_uu) {
      const int i1 = __shfl(i1_l, l);
      const unsigned int q1 = t1[i1 * (E_DIM / 2) + lane];
      h0 += lo_bf(q1);
      h1 += hi_bf(q1);
    }
    o0 += a * h0;
    o1 += a * h1;
  }
  // sum_l a_l = 1  =>  out = scale * (self + sum a*g0 + sum a*g1)
  const float r0 = fmaxf((self.x + o0) * scale, 0.f);
  const float r1 = fmaxf((self.y + o1) * scale, 0.f);
  *(float2*)(feats + ((long)k * B + b) * E_DIM + lane * 2) =
      make_float2(r0, r1);

  // ---- inter(): hid[j] = b0[j] + sum_e r[e] * W0[e][j] ----
  sc[wv][lane * 2] = r0;
  sc[wv][lane * 2 + 1] = r1;
  __syncthreads();

  float hid = b0[lane];
#pragma unroll 4
  for (int e = 0; e < E_DIM; ++e) hid += sc[wv][e] * W0[e * HDIM + lane];
  const float pp = tanhf(hid) * w1[lane];
  const float sum = waveSum(pp);
  if (lane == 0) partials[(long)k * B + b] = sum;
}

// Fallback (proven R4 kernel): fp32 gathers, used only if ws is too small.
__global__ __launch_bounds__(256) void phase1_f32(
    const float* __restrict__ user_embs, const float* __restrict__ item_embs,
    const float* __restrict__ w_uu, const float* __restrict__ w_uiu,
    const float* __restrict__ w_uui, const float* __restrict__ W0,
    const float* __restrict__ b0, const float* __restrict__ w1,
    const int* __restrict__ uid, const int* __restrict__ nbr,
    const int* __restrict__ uiu, const int* __restrict__ uui,
    float* __restrict__ feats, float* __restrict__ partials, int B) {
  const int lane = threadIdx.x & 63;
  const int wv = threadIdx.x >> 6;
  const int w_id = blockIdx.x * 4 + wv;
  const int b = w_id / 3;
  const int k = w_id - 3 * b;
  if (b >= B) return;

  __shared__ float sc[4][E_DIM];
  const int u = uid[b];
  const float self0 = user_embs[u * E_DIM + lane];
  const float self1 = user_embs[u * E_DIM + 64 + lane];
  const float* w = (k == 0) ? w_uu : (k == 1) ? w_uiu : w_uui;
  const float wa0 = w[lane], wa1 = w[64 + lane];
  const float wb0 = w[128 + lane], wb1 = w[192 + lane];
  const float logit_self = waveSum(self0 * wa0 + self1 * wa1);
  const bool is_uu = (k == 0);
  const float scale = is_uu ? 0.5f : (1.0f / 3.0f);
  const float* t0 = (k == 1) ? item_embs : user_embs;
  const float* t1 = (k == 1) ? user_embs : item_embs;
  int i0_l, i1_l;
  if (is_uu) {
    i0_l = nbr[b * L_DIM + lane];
    i1_l = 0;
  } else {
    const int* mp = (k == 1) ? uiu : uui;
    i0_l = mp[(b * 2 + 0) * L_DIM + lane];
    i1_l = mp[(b * 2 + 1) * L_DIM + lane];
  }
  const float mask_l = (i0_l == 0) ? 1.0f : 0.0f;
  float m = -3.0e38f, s = 0.0f, o0 = 0.0f, o1 = 0.0f;
  int i0 = __shfl(i0_l, 0), i1 = __shfl(i1_l, 0);
  float g00 = t0[i0 * E_DIM + lane];
  float g01 = t0[i0 * E_DIM + 64 + lane];
  float g10 = 0.f, g11 = 0.f;
  if (!is_uu) {
    g10 = t1[i1 * E_DIM + lane];
    g11 = t1[i1 * E_DIM + 64 + lane];
  }
  for (int l = 0; l < L_DIM; ++l) {
    const float f0 = (self0 + g00 + g10) * scale;
    const float f1 = (self1 + g01 + g11) * scale;
    if (l < L_DIM - 1) {
      i0 = __shfl(i0_l, l + 1);
      i1 = __shfl(i1_l, l + 1);
      g00 = t0[i0 * E_DIM + lane];
      g01 = t0[i0 * E_DIM + 64 + lane];
      if (!is_uu) {
        g10 = t1[i1 * E_DIM + lane];
        g11 = t1[i1 * E_DIM + 64 + lane];
      }
    }
    float logit = waveSum(f0 * wb0 + f1 * wb1) + logit_self;
    logit = (logit > 0.f) ? logit : 0.01f * logit;
    logit += -100000000.0f * __shfl(mask_l, l);
    const float mn = fmaxf(m, logit);
    const float alpha = __expf(m - mn);
    const float p = __expf(logit - mn);
    s = s * alpha + p;
    o0 = o0 * alpha + p * f0;
    o1 = o1 * alpha + p * f1;
    m = mn;
  }
  const float inv_s = 1.0f / s;
  const float r0 = fmaxf(o0 * inv_s, 0.f);
  const float r1 = fmaxf(o1 * inv_s, 0.f);
  feats[((long)k * B + b) * E_DIM + lane] = r0;
  feats[((long)k * B + b) * E_DIM + 64 + lane] = r1;
  sc[wv][lane] = r0;
  sc[wv][64 + lane] = r1;
  __syncthreads();
  float hid = b0[lane];
#pragma unroll 4
  for (int e = 0; e < E_DIM; ++e) hid += sc[wv][e] * W0[e * HDIM + lane];
  const float p = tanhf(hid) * w1[lane];
  const float sum = waveSum(p);
  if (lane == 0) partials[(long)k * B + b] = sum;
}

__global__ __launch_bounds__(256) void reduce_scores(
    const float* __restrict__ partials, float* __restrict__ weights, int B) {
  __shared__ float red[256];
  const int tid = threadIdx.x;
  float s[3];
#pragma unroll
  for (int k = 0; k < 3; ++k) {
    float acc = 0.f;
    for (int i = tid; i < B; i += 256) acc += partials[(long)k * B + i];
    red[tid] = acc;
    __syncthreads();
    for (int off = 128; off > 0; off >>= 1) {
      if (tid < off) red[tid] += red[tid + off];
      __syncthreads();
    }
    s[k] = red[0];
    __syncthreads();
  }
  if (tid == 0) {
    const float inv_b = 1.0f / (float)B;
    const float s0 = s[0] * inv_b, s1 = s[1] * inv_b, s2 = s[2] * inv_b;
    const float m = fmaxf(s0, fmaxf(s1, s2));
    const float e0 = __expf(s0 - m);
    const float e1 = __expf(s1 - m);
    const float e2 = __expf(s2 - m);
    const float inv = 1.0f / (e0 + e1 + e2);
    weights[0] = e0 * inv;
    weights[1] = e1 * inv;
    weights[2] = e2 * inv;
  }
}

__global__ __launch_bounds__(256) void phase2(
    const float* __restrict__ feats, const float* __restrict__ weights,
    float* __restrict__ out, int B) {
  const int i = blockIdx.x * blockDim.x + threadIdx.x;
  const int n = B * E_DIM;
  if (i >= n) return;
  const float w0 = weights[0], w1 = weights[1], w2 = weights[2];
  const float v = w0 * feats[i] + w1 * feats[n + i] + w2 * feats[2 * n + i];
  out[i] = fmaxf(v, 0.f);
}

extern "C" void kernel_launch(void* const* d_in, const int* in_sizes, int n_in,
                              void* d_out, int out_size, void* d_ws,
                              size_t ws_size, hipStream_t stream) {
  const float* user_embs = (const float*)d_in[0];
  const float* item_embs = (const float*)d_in[1];
  const float* w_uu = (const float*)d_in[2];
  const float* w_uiu = (const float*)d_in[3];
  const float* w_uui = (const float*)d_in[4];
  const float* W0 = (const float*)d_in[5];
  const float* b0 = (const float*)d_in[6];
  const float* w1 = (const float*)d_in[7];
  const int* uid = (const int*)d_in[8];
  const int* nbr = (const int*)d_in[9];
  const int* uiu = (const int*)d_in[10];
  const int* uui = (const int*)d_in[11];
  const int B = in_sizes[8];
  const int nU = in_sizes[0];         // user table elems
  const int nI = in_sizes[1];         // item table elems
  const int nUr = nU / E_DIM;         // user rows
  const int nIr = nI / E_DIM;         // item rows

  float* ws = (float*)d_ws;
  float* partials = ws;            // [3][B]
  float* weights = ws + 3 * B;     // [3] (+pad)
  float* feats = ws + 3 * B + 64;  // [3][B][E]
  const size_t f32_floats = (size_t)3 * B + 64 + (size_t)3 * B * E_DIM;
  unsigned short* user_bf = (unsigned short*)(ws + f32_floats);
  unsigned short* item_bf = user_bf + nU;
  float* projU0 = (float*)(item_bf + nI);  // nU, nI even -> 4B aligned
  float* projU1 = projU0 + nUr;
  float* projU2 = projU1 + nUr;
  float* projI1 = projU2 + nUr;
  float* projI2 = projI1 + nIr;
  const size_t need = f32_floats * 4 + ((size_t)nU + nI) * 2 +
                      ((size_t)3 * nUr + 2 * nIr) * 4;

  const int n_waves = 3 * B;
  const int n_blocks = (n_waves + 3) / 4;

  if (ws_size >= need) {
    convert_proj<<<(nUr + 3) / 4, 256, 0, stream>>>(
        user_embs, user_bf, w_uu, w_uiu, w_uui, projU0, projU1, projU2, nUr,
        3);
    convert_proj<<<(nIr + 3) / 4, 256, 0, stream>>>(
        item_embs, item_bf, w_uiu, w_uui, w_uui, projI1, projI2, projI2, nIr,
        2);
    phase1_proj<<<n_blocks, 256, 0, stream>>>(
        user_embs, user_bf, item_bf, projU0, projU1, projU2, projI1, projI2,
        w_uu, w_uiu, w_uui, W0, b0, w1, uid, nbr, uiu, uui, feats, partials,
        B);
  } else {
    phase1_f32<<<n_blocks, 256, 0, stream>>>(user_embs, item_embs, w_uu,
                                             w_uiu, w_uui, W0, b0, w1, uid,
                                             nbr, uiu, uui, feats, partials, B);
  }
  reduce_scores<<<1, 256, 0, stream>>>(partials, weights, B);
  const int n = B * E_DIM;
  phase2<<<(n + 255) / 256, 256, 0, stream>>>(feats, weights, (float*)d_out, B);
}

// Round 8
// 260.991 us; speedup vs baseline: 1.0772x; 1.0772x over previous
//
#include <hip/hip_runtime.h>
#include <hip/hip_bf16.h>

#define E_DIM 128
#define L_DIM 64
#define HDIM 64

__device__ __forceinline__ float waveSum(float v) {
#pragma unroll
  for (int o = 32; o > 0; o >>= 1) v += __shfl_xor(v, o);
  return v;
}
__device__ __forceinline__ float waveMax(float v) {
#pragma unroll
  for (int o = 32; o > 0; o >>= 1) v = fmaxf(v, __shfl_xor(v, o));
  return v;
}
__device__ __forceinline__ float halfSum(float v) {  // reduce within 32 lanes
#pragma unroll
  for (int o = 16; o > 0; o >>= 1) v += __shfl_xor(v, o);
  return v;
}

__device__ __forceinline__ unsigned int f2bf(float f) {  // RNE
  unsigned int u = __float_as_uint(f);
  return (u + 0x7fffu + ((u >> 16) & 1u)) >> 16;
}
__device__ __forceinline__ float lo_bf(unsigned int q) {
  return __uint_as_float(q << 16);
}
__device__ __forceinline__ float hi_bf(unsigned int q) {
  return __uint_as_float(q & 0xffff0000u);
}

// Two rows per wave: half-wave h handles row 2*gw+h; lane j=lane&31 covers
// dims 4j..4j+3 (float4 read, 2-dword bf16 write). Projection dots reduced
// over 32-lane halves (5 butterfly stages for 2 rows).
__global__ __launch_bounds__(256) void convert_proj(
    const float* __restrict__ src, unsigned short* __restrict__ dst,
    const float* __restrict__ wA, const float* __restrict__ wB,
    const float* __restrict__ wC, float* __restrict__ pA,
    float* __restrict__ pB, float* __restrict__ pC, int rows, int nproj) {
  const int lane = threadIdx.x & 63;
  const int j = lane & 31;
  const int h = lane >> 5;
  const int gw = blockIdx.x * 4 + (threadIdx.x >> 6);
  const int r = gw * 2 + h;
  if (r >= rows) return;

  const float4 v = *(const float4*)(src + (long)r * E_DIM + j * 4);
  const unsigned int b0p = f2bf(v.x) | (f2bf(v.y) << 16);
  const unsigned int b1p = f2bf(v.z) | (f2bf(v.w) << 16);
  ((uint2*)dst)[(long)r * (E_DIM / 4) + j] = make_uint2(b0p, b1p);
  const float x0 = lo_bf(b0p), x1 = hi_bf(b0p);
  const float x2 = lo_bf(b1p), x3 = hi_bf(b1p);

  const float4 a4 = *(const float4*)(wA + E_DIM + j * 4);
  const float dA = halfSum(x0 * a4.x + x1 * a4.y + x2 * a4.z + x3 * a4.w);
  const float4 b4 = *(const float4*)(wB + E_DIM + j * 4);
  const float dB = halfSum(x0 * b4.x + x1 * b4.y + x2 * b4.z + x3 * b4.w);
  float dC = 0.f;
  if (nproj == 3) {
    const float4 c4 = *(const float4*)(wC + E_DIM + j * 4);
    dC = halfSum(x0 * c4.x + x1 * c4.y + x2 * c4.z + x3 * c4.w);
  }
  if (j == 0) {
    pA[r] = dA;
    pB[r] = dB;
    if (nproj == 3) pC[r] = dC;
  }
}

// One wave per (b, k). Logits via precomputed row projections; softmax =
// 2 butterflies; weighted sum processes 2 rows/iteration (half-wave each)
// with a depth-8 rolling load pipeline.
__global__ __launch_bounds__(256) void phase1_proj(
    const float* __restrict__ user_embs,  // fp32 (self rows)
    const unsigned short* __restrict__ user_bf,
    const unsigned short* __restrict__ item_bf,
    const float* __restrict__ projU0, const float* __restrict__ projU1,
    const float* __restrict__ projU2, const float* __restrict__ projI1,
    const float* __restrict__ projI2,
    const float* __restrict__ w_uu, const float* __restrict__ w_uiu,
    const float* __restrict__ w_uui, const float* __restrict__ W0,
    const float* __restrict__ b0, const float* __restrict__ w1,
    const int* __restrict__ uid, const int* __restrict__ nbr,
    const int* __restrict__ uiu, const int* __restrict__ uui,
    float* __restrict__ feats,     // [3][B][E]
    float* __restrict__ partials,  // [3][B]
    int B) {
  const int lane = threadIdx.x & 63;
  const int j = lane & 31;
  const int half = lane >> 5;
  const int wv = threadIdx.x >> 6;
  const int w_id = blockIdx.x * 4 + wv;
  const int b = w_id / 3;
  const int k = w_id - 3 * b;
  if (b >= B) return;  // grid exact for B%4==0

  __shared__ float sc[4][E_DIM];

  const int u = uid[b];
  const float2 self2 = *(const float2*)(user_embs + (long)u * E_DIM + lane * 2);

  const float* w = (k == 0) ? w_uu : (k == 1) ? w_uiu : w_uui;
  const float2 wa = *(const float2*)(w + lane * 2);
  const float2 wb = *(const float2*)(w + E_DIM + lane * 2);
  const float S1 = waveSum(self2.x * wa.x + self2.y * wa.y);
  const float S2 = waveSum(self2.x * wb.x + self2.y * wb.y);

  const bool is_uu = (k == 0);
  const float scale = is_uu ? 0.5f : (1.0f / 3.0f);
  // tables: k==0 -> user; k==1 (uiu) -> item,user; k==2 (uui) -> user,item
  const uint2* T0 = (const uint2*)((k == 1) ? item_bf : user_bf);
  const uint2* T1 = (const uint2*)((k == 1) ? user_bf : item_bf);
  const float* p0 = (k == 0) ? projU0 : (k == 1) ? projI1 : projU2;
  const float* p1 = (k == 1) ? projU1 : projI2;  // unused for k==0

  // lane l owns neighbor l's indices (coalesced)
  int i0_l, i1_l;
  if (is_uu) {
    i0_l = nbr[b * L_DIM + lane];
    i1_l = 0;
  } else {
    const int* mp = (k == 1) ? uiu : uui;
    i0_l = mp[(b * 2 + 0) * L_DIM + lane];
    i1_l = mp[(b * 2 + 1) * L_DIM + lane];
  }

  // ---- logits from projections (lane = neighbor) ----
  float d = p0[i0_l];
  if (!is_uu) d += p1[i1_l];
  float logit = S1 + scale * (S2 + d);
  logit = (logit > 0.f) ? logit : 0.01f * logit;  // leaky_relu
  if (i0_l == 0) logit += -100000000.0f;          // mask

  const float M = waveMax(logit);
  const float p = __expf(logit - M);
  const float Z = waveSum(p);
  const float a_l = p / Z;  // lane l: neighbor l's attention weight

  // ---- weighted sum: 2 rows/iter (half-wave each), depth-8 pipeline ----
  constexpr int PD = 8;
  constexpr int RQ = E_DIM / 4;  // 32 uint2 per row
  uint2 q0[PD], q1[PD];
  float av[PD];
  float o0 = 0.f, o1 = 0.f, o2 = 0.f, o3 = 0.f;

#pragma unroll
  for (int it = 0; it < PD; ++it) {
    const int l2 = 2 * it + half;
    av[it] = __shfl(a_l, l2);
    const int i0 = __shfl(i0_l, l2);
    q0[it] = T0[(long)i0 * RQ + j];
    if (!is_uu) {
      const int i1 = __shfl(i1_l, l2);
      q1[it] = T1[(long)i1 * RQ + j];
    }
  }
#pragma unroll
  for (int it = 0; it < L_DIM / 2; ++it) {
    const int pi = it & (PD - 1);
    const float a = av[pi];
    const uint2 q = q0[pi];
    float h0 = lo_bf(q.x), h1 = hi_bf(q.x);
    float h2 = lo_bf(q.y), h3 = hi_bf(q.y);
    if (!is_uu) {
      const uint2 r = q1[pi];
      h0 += lo_bf(r.x); h1 += hi_bf(r.x);
      h2 += lo_bf(r.y); h3 += hi_bf(r.y);
    }
    o0 += a * h0; o1 += a * h1; o2 += a * h2; o3 += a * h3;
    const int nit = it + PD;
    if (nit < L_DIM / 2) {
      const int l2 = 2 * nit + half;
      av[pi] = __shfl(a_l, l2);
      const int i0 = __shfl(i0_l, l2);
      q0[pi] = T0[(long)i0 * RQ + j];
      if (!is_uu) {
        const int i1 = __shfl(i1_l, l2);
        q1[pi] = T1[(long)i1 * RQ + j];
      }
    }
  }
  // combine the two halves (each summed 32 of the 64 neighbors)
  o0 += __shfl_xor(o0, 32);
  o1 += __shfl_xor(o1, 32);
  o2 += __shfl_xor(o2, 32);
  o3 += __shfl_xor(o3, 32);

  // sum_l a_l = 1  =>  out = scale * (self + sum a*(g0[+g1]))
  const float4 s4 = *(const float4*)(user_embs + (long)u * E_DIM + j * 4);
  float4 r4;
  r4.x = fmaxf((s4.x + o0) * scale, 0.f);
  r4.y = fmaxf((s4.y + o1) * scale, 0.f);
  r4.z = fmaxf((s4.z + o2) * scale, 0.f);
  r4.w = fmaxf((s4.w + o3) * scale, 0.f);
  if (half == 0) {
    *(float4*)(feats + ((long)k * B + b) * E_DIM + j * 4) = r4;
    *(float4*)(&sc[wv][j * 4]) = r4;
  }
  __syncthreads();

  // ---- inter(): hid[j] = b0[j] + sum_e r[e] * W0[e][j] ----
  float hid = b0[lane];
#pragma unroll 4
  for (int e = 0; e < E_DIM; ++e) hid += sc[wv][e] * W0[e * HDIM + lane];
  const float pp = tanhf(hid) * w1[lane];
  const float sum = waveSum(pp);
  if (lane == 0) partials[(long)k * B + b] = sum;
}

// Fallback (proven R4 kernel): fp32 gathers, used only if ws is too small.
__global__ __launch_bounds__(256) void phase1_f32(
    const float* __restrict__ user_embs, const float* __restrict__ item_embs,
    const float* __restrict__ w_uu, const float* __restrict__ w_uiu,
    const float* __restrict__ w_uui, const float* __restrict__ W0,
    const float* __restrict__ b0, const float* __restrict__ w1,
    const int* __restrict__ uid, const int* __restrict__ nbr,
    const int* __restrict__ uiu, const int* __restrict__ uui,
    float* __restrict__ feats, float* __restrict__ partials, int B) {
  const int lane = threadIdx.x & 63;
  const int wv = threadIdx.x >> 6;
  const int w_id = blockIdx.x * 4 + wv;
  const int b = w_id / 3;
  const int k = w_id - 3 * b;
  if (b >= B) return;

  __shared__ float sc[4][E_DIM];
  const int u = uid[b];
  const float self0 = user_embs[u * E_DIM + lane];
  const float self1 = user_embs[u * E_DIM + 64 + lane];
  const float* w = (k == 0) ? w_uu : (k == 1) ? w_uiu : w_uui;
  const float wa0 = w[lane], wa1 = w[64 + lane];
  const float wb0 = w[128 + lane], wb1 = w[192 + lane];
  const float logit_self = waveSum(self0 * wa0 + self1 * wa1);
  const bool is_uu = (k == 0);
  const float scale = is_uu ? 0.5f : (1.0f / 3.0f);
  const float* t0 = (k == 1) ? item_embs : user_embs;
  const float* t1 = (k == 1) ? user_embs : item_embs;
  int i0_l, i1_l;
  if (is_uu) {
    i0_l = nbr[b * L_DIM + lane];
    i1_l = 0;
  } else {
    const int* mp = (k == 1) ? uiu : uui;
    i0_l = mp[(b * 2 + 0) * L_DIM + lane];
    i1_l = mp[(b * 2 + 1) * L_DIM + lane];
  }
  const float mask_l = (i0_l == 0) ? 1.0f : 0.0f;
  float m = -3.0e38f, s = 0.0f, o0 = 0.0f, o1 = 0.0f;
  int i0 = __shfl(i0_l, 0), i1 = __shfl(i1_l, 0);
  float g00 = t0[i0 * E_DIM + lane];
  float g01 = t0[i0 * E_DIM + 64 + lane];
  float g10 = 0.f, g11 = 0.f;
  if (!is_uu) {
    g10 = t1[i1 * E_DIM + lane];
    g11 = t1[i1 * E_DIM + 64 + lane];
  }
  for (int l = 0; l < L_DIM; ++l) {
    const float f0 = (self0 + g00 + g10) * scale;
    const float f1 = (self1 + g01 + g11) * scale;
    if (l < L_DIM - 1) {
      i0 = __shfl(i0_l, l + 1);
      i1 = __shfl(i1_l, l + 1);
      g00 = t0[i0 * E_DIM + lane];
      g01 = t0[i0 * E_DIM + 64 + lane];
      if (!is_uu) {
        g10 = t1[i1 * E_DIM + lane];
        g11 = t1[i1 * E_DIM + 64 + lane];
      }
    }
    float logit = waveSum(f0 * wb0 + f1 * wb1) + logit_self;
    logit = (logit > 0.f) ? logit : 0.01f * logit;
    logit += -100000000.0f * __shfl(mask_l, l);
    const float mn = fmaxf(m, logit);
    const float alpha = __expf(m - mn);
    const float p = __expf(logit - mn);
    s = s * alpha + p;
    o0 = o0 * alpha + p * f0;
    o1 = o1 * alpha + p * f1;
    m = mn;
  }
  const float inv_s = 1.0f / s;
  const float r0 = fmaxf(o0 * inv_s, 0.f);
  const float r1 = fmaxf(o1 * inv_s, 0.f);
  feats[((long)k * B + b) * E_DIM + lane] = r0;
  feats[((long)k * B + b) * E_DIM + 64 + lane] = r1;
  sc[wv][lane] = r0;
  sc[wv][64 + lane] = r1;
  __syncthreads();
  float hid = b0[lane];
#pragma unroll 4
  for (int e = 0; e < E_DIM; ++e) hid += sc[wv][e] * W0[e * HDIM + lane];
  const float p = tanhf(hid) * w1[lane];
  const float sum = waveSum(p);
  if (lane == 0) partials[(long)k * B + b] = sum;
}

__global__ __launch_bounds__(256) void reduce_scores(
    const float* __restrict__ partials, float* __restrict__ weights, int B) {
  __shared__ float red[256];
  const int tid = threadIdx.x;
  float s[3];
#pragma unroll
  for (int k = 0; k < 3; ++k) {
    float acc = 0.f;
    for (int i = tid; i < B; i += 256) acc += partials[(long)k * B + i];
    red[tid] = acc;
    __syncthreads();
    for (int off = 128; off > 0; off >>= 1) {
      if (tid < off) red[tid] += red[tid + off];
      __syncthreads();
    }
    s[k] = red[0];
    __syncthreads();
  }
  if (tid == 0) {
    const float inv_b = 1.0f / (float)B;
    const float s0 = s[0] * inv_b, s1 = s[1] * inv_b, s2 = s[2] * inv_b;
    const float m = fmaxf(s0, fmaxf(s1, s2));
    const float e0 = __expf(s0 - m);
    const float e1 = __expf(s1 - m);
    const float e2 = __expf(s2 - m);
    const float inv = 1.0f / (e0 + e1 + e2);
    weights[0] = e0 * inv;
    weights[1] = e1 * inv;
    weights[2] = e2 * inv;
  }
}

__global__ __launch_bounds__(256) void phase2(
    const float* __restrict__ feats, const float* __restrict__ weights,
    float* __restrict__ out, int B) {
  const int i = blockIdx.x * blockDim.x + threadIdx.x;
  const int n = B * E_DIM;
  if (i >= n) return;
  const float w0 = weights[0], w1 = weights[1], w2 = weights[2];
  const float v = w0 * feats[i] + w1 * feats[n + i] + w2 * feats[2 * n + i];
  out[i] = fmaxf(v, 0.f);
}

extern "C" void kernel_launch(void* const* d_in, const int* in_sizes, int n_in,
                              void* d_out, int out_size, void* d_ws,
                              size_t ws_size, hipStream_t stream) {
  const float* user_embs = (const float*)d_in[0];
  const float* item_embs = (const float*)d_in[1];
  const float* w_uu = (const float*)d_in[2];
  const float* w_uiu = (const float*)d_in[3];
  const float* w_uui = (const float*)d_in[4];
  const float* W0 = (const float*)d_in[5];
  const float* b0 = (const float*)d_in[6];
  const float* w1 = (const float*)d_in[7];
  const int* uid = (const int*)d_in[8];
  const int* nbr = (const int*)d_in[9];
  const int* uiu = (const int*)d_in[10];
  const int* uui = (const int*)d_in[11];
  const int B = in_sizes[8];
  const int nU = in_sizes[0];  // user table elems
  const int nI = in_sizes[1];  // item table elems
  const int nUr = nU / E_DIM;  // user rows
  const int nIr = nI / E_DIM;  // item rows

  float* ws = (float*)d_ws;
  float* partials = ws;            // [3][B]
  float* weights = ws + 3 * B;     // [3] (+pad)
  float* feats = ws + 3 * B + 64;  // [3][B][E]
  const size_t f32_floats = (size_t)3 * B + 64 + (size_t)3 * B * E_DIM;
  unsigned short* user_bf = (unsigned short*)(ws + f32_floats);
  unsigned short* item_bf = user_bf + nU;
  float* projU0 = (float*)(item_bf + nI);
  float* projU1 = projU0 + nUr;
  float* projU2 = projU1 + nUr;
  float* projI1 = projU2 + nUr;
  float* projI2 = projI1 + nIr;
  const size_t need = f32_floats * 4 + ((size_t)nU + nI) * 2 +
                      ((size_t)3 * nUr + 2 * nIr) * 4;

  const int n_waves = 3 * B;
  const int n_blocks = (n_waves + 3) / 4;

  if (ws_size >= need) {
    convert_proj<<<(nUr / 2 + 3) / 4, 256, 0, stream>>>(
        user_embs, user_bf, w_uu, w_uiu, w_uui, projU0, projU1, projU2, nUr,
        3);
    convert_proj<<<(nIr / 2 + 3) / 4, 256, 0, stream>>>(
        item_embs, item_bf, w_uiu, w_uui, w_uui, projI1, projI2, projI2, nIr,
        2);
    phase1_proj<<<n_blocks, 256, 0, stream>>>(
        user_embs, user_bf, item_bf, projU0, projU1, projU2, projI1, projI2,
        w_uu, w_uiu, w_uui, W0, b0, w1, uid, nbr, uiu, uui, feats, partials,
        B);
  } else {
    phase1_f32<<<n_blocks, 256, 0, stream>>>(user_embs, item_embs, w_uu,
                                             w_uiu, w_uui, W0, b0, w1, uid,
                                             nbr, uiu, uui, feats, partials, B);
  }
  reduce_scores<<<1, 256, 0, stream>>>(partials, weights, B);
  const int n = B * E_DIM;
  phase2<<<(n + 255) / 256, 256, 0, stream>>>(feats, weights, (float*)d_out, B);
}